// Round 8
// baseline (1038.650 us; speedup 1.0000x reference)
//
#include <hip/hip_runtime.h>
#include <math.h>

// Problem constants
#define B_   32
#define L_   128
#define W_   16
#define CE_  64     // char embed
#define NF_  128    // num filters
#define WE_  256    // word embed
#define E_   384    // NF_ + WE_
#define H_   512
#define G4_  2048   // 4*H
#define O1_  512
#define NC_  17
#define LSTM_BLOCKS 64          // 32 per direction
#define AGENT_SC __HIP_MEMORY_SCOPE_AGENT

typedef __attribute__((ext_vector_type(4))) float f32x4;
typedef _Float16 half8 __attribute__((ext_vector_type(8)));
typedef _Float16 half4 __attribute__((ext_vector_type(4)));

__device__ inline half8 cvt8(float4 a, float4 b) {
    half8 r;
    r[0] = (_Float16)a.x; r[1] = (_Float16)a.y;
    r[2] = (_Float16)a.z; r[3] = (_Float16)a.w;
    r[4] = (_Float16)b.x; r[5] = (_Float16)b.y;
    r[6] = (_Float16)b.z; r[7] = (_Float16)b.w;
    return r;
}

// sc1 (agent-coherent, MALL-direct) loads via inline asm
__device__ inline unsigned int ld_u32_sc1(const unsigned int* p) {
    unsigned int v;
    asm volatile("global_load_dword %0, %1, off sc1\n\ts_waitcnt vmcnt(0)"
                 : "=v"(v) : "v"(p) : "memory");
    return v;
}
__device__ inline half8 ld_b128_sc1(const void* p) {
    half8 v;
    asm volatile("global_load_dwordx4 %0, %1, off sc1"
                 : "=v"(v) : "v"(p) : "memory");
    return v;
}

__device__ inline float sigm_f(float x) { return 1.f / (1.f + __expf(-x)); }
__device__ inline float tanh_f(float x) { return 2.f / (1.f + __expf(-2.f * x)) - 1.f; }

// ---------------------------------------------------------------------------
// Kernel 0: transpose conv weights [F][C][K] -> [C][K][F]
// ---------------------------------------------------------------------------
__global__ __launch_bounds__(256) void conv_transpose_k(
    const float* __restrict__ cw, float* __restrict__ cwT)
{
    int i = blockIdx.x * 256 + threadIdx.x;   // 24576 exact
    int f = i / 192;
    int rem = i - f * 192;
    int c = rem / 3;
    int k = rem - c * 3;
    cwT[(c * 3 + k) * NF_ + f] = cw[i];
}

// ---------------------------------------------------------------------------
// Kernel 1: char embed gather + conv1d(k=3,pad=1) + relu + maxpool + word
// embed concat -> x_h [B*L, 384] fp16
// ---------------------------------------------------------------------------
__global__ __launch_bounds__(64) void embed_cnn(
    const int* __restrict__ word_ids, const int* __restrict__ char_ids,
    const float* __restrict__ char_emb, const float* __restrict__ word_emb,
    const float* __restrict__ cwT, const float* __restrict__ conv_b,
    _Float16* __restrict__ x_h)
{
    __shared__ float ce[CE_][20];
    __shared__ int ids[W_];
    int bl = blockIdx.x;
    int tid = threadIdx.x;

    if (tid < W_) ids[tid] = char_ids[bl * W_ + tid];
    ce[tid][0] = 0.f;
    ce[tid][17] = 0.f;
    __syncthreads();

    for (int i = tid; i < W_ * CE_; i += 64) {
        int w = i >> 6, c = i & 63;
        ce[c][w + 1] = char_emb[ids[w] * CE_ + c];
    }
    __syncthreads();

    int f0 = tid, f1 = tid + 64;
    float acc0[W_], acc1[W_];
#pragma unroll
    for (int w = 0; w < W_; w++) { acc0[w] = 0.f; acc1[w] = 0.f; }

    for (int c = 0; c < CE_; c++) {
        float win[18];
        float4 v0 = *(const float4*)&ce[c][0];
        float4 v1 = *(const float4*)&ce[c][4];
        float4 v2 = *(const float4*)&ce[c][8];
        float4 v3 = *(const float4*)&ce[c][12];
        win[0]=v0.x; win[1]=v0.y; win[2]=v0.z; win[3]=v0.w;
        win[4]=v1.x; win[5]=v1.y; win[6]=v1.z; win[7]=v1.w;
        win[8]=v2.x; win[9]=v2.y; win[10]=v2.z; win[11]=v2.w;
        win[12]=v3.x; win[13]=v3.y; win[14]=v3.z; win[15]=v3.w;
        win[16] = ce[c][16];
        win[17] = ce[c][17];
        const float* wp = cwT + c * 3 * NF_;
        float k00 = wp[f0], k01 = wp[NF_ + f0], k02 = wp[2 * NF_ + f0];
        float k10 = wp[f1], k11 = wp[NF_ + f1], k12 = wp[2 * NF_ + f1];
#pragma unroll
        for (int w = 0; w < W_; w++) {
            acc0[w] += win[w] * k00 + win[w + 1] * k01 + win[w + 2] * k02;
            acc1[w] += win[w] * k10 + win[w + 1] * k11 + win[w + 2] * k12;
        }
    }
    float m0 = acc0[0], m1 = acc1[0];
#pragma unroll
    for (int w = 1; w < W_; w++) { m0 = fmaxf(m0, acc0[w]); m1 = fmaxf(m1, acc1[w]); }
    m0 = fmaxf(0.f, m0 + conv_b[f0]);
    m1 = fmaxf(0.f, m1 + conv_b[f1]);
    x_h[bl * E_ + f0] = (_Float16)m0;
    x_h[bl * E_ + f1] = (_Float16)m1;

    int wid = word_ids[bl];
    float4 wv = *(const float4*)&word_emb[wid * WE_ + tid * 4];
    half4 h;
    h[0] = (_Float16)wv.x; h[1] = (_Float16)wv.y;
    h[2] = (_Float16)wv.z; h[3] = (_Float16)wv.w;
    *(half4*)&x_h[bl * E_ + NF_ + tid * 4] = h;
}

// ---------------------------------------------------------------------------
// Kernel 2: fp16 MFMA GEMM  C = A[M,K]h @ W[N,K]f32^T + bias.
// ---------------------------------------------------------------------------
__global__ __launch_bounds__(256) void gemm_f16(
    const _Float16* __restrict__ A, const float* __restrict__ Wt,
    const float* __restrict__ bias, void* __restrict__ C,
    int N, int K, int mode, int act, int fp16out)
{
    __shared__ _Float16 As[64 * 32];
    __shared__ _Float16 Bs[64 * 32];
    int tid = threadIdx.x;
    int bm = blockIdx.x * 64;
    int bn = blockIdx.y * 64;
    int l = tid & 63;
    int mt = tid >> 6;             // wave id = m-tile
    int lr = l & 15, lk = l >> 4;

    int srow = tid >> 2, skq = (tid & 3) << 3;   // staging: row 0..63, k 0..31
    int sbyteA = ((srow * 64 + skq * 2) ^ ((srow & 7) << 4));

    f32x4 d[4] = {{0.f,0.f,0.f,0.f},{0.f,0.f,0.f,0.f},
                  {0.f,0.f,0.f,0.f},{0.f,0.f,0.f,0.f}};

    for (int kt = 0; kt < K; kt += 32) {
        half8 av = *(const half8*)&A[(size_t)(bm + srow) * K + kt + skq];
        const float* wp = &Wt[(size_t)(bn + srow) * K + kt + skq];
        float4 w0 = *(const float4*)wp;
        float4 w1 = *(const float4*)(wp + 4);
        *(half8*)((char*)As + sbyteA) = av;
        *(half8*)((char*)Bs + sbyteA) = cvt8(w0, w1);
        __syncthreads();

        int arow = mt * 16 + lr;
        half8 af = *(const half8*)((char*)As +
                     ((arow * 64 + lk * 16) ^ ((arow & 7) << 4)));
#pragma unroll
        for (int nt = 0; nt < 4; nt++) {
            int brow = nt * 16 + lr;
            half8 bf = *(const half8*)((char*)Bs +
                         ((brow * 64 + lk * 16) ^ ((brow & 7) << 4)));
            d[nt] = __builtin_amdgcn_mfma_f32_16x16x32_f16(af, bf, d[nt], 0, 0, 0);
        }
        __syncthreads();
    }

#pragma unroll
    for (int nt = 0; nt < 4; nt++) {
        int n = bn + nt * 16 + lr;
        float bv = bias[n];
#pragma unroll
        for (int r = 0; r < 4; r++) {
            int m = bm + mt * 16 + lk * 4 + r;
            int orow;
            if (mode == 0) orow = m;
            else {
                int bb = m >> 7, ll = m & 127;
                if (mode == 2) ll = 127 - ll;
                orow = ll * B_ + bb;
            }
            float v = d[nt][r] + bv;
            if (act) v = v > 0.f ? v : expm1f(v);
            if (fp16out) ((_Float16*)C)[(size_t)orow * N + n] = (_Float16)v;
            else         ((float*)C)[(size_t)orow * N + n] = v;
        }
    }
}

// ---------------------------------------------------------------------------
// Kernel 2b: small fp32 GEMM for the head2 (N=17)
// ---------------------------------------------------------------------------
__global__ __launch_bounds__(256) void gemm_bias_act(
    const float* __restrict__ A, const float* __restrict__ Wt,
    const float* __restrict__ bias, float* __restrict__ C,
    int M, int N, int K)
{
    __shared__ float As[16][68];
    __shared__ float Bs[16][68];
    int tid = threadIdx.x;
    int bm = blockIdx.x * 64;
    int bn = blockIdx.y * 64;
    int tx = tid & 15, ty = tid >> 4;
    int r = tid >> 2, kq = (tid & 3) << 2;
    float acc[4][4] = {};

    for (int kt = 0; kt < K; kt += 16) {
        float4 av = *(const float4*)&A[(bm + r) * K + kt + kq];
        As[kq + 0][r] = av.x; As[kq + 1][r] = av.y;
        As[kq + 2][r] = av.z; As[kq + 3][r] = av.w;
        int n = bn + r;
        float4 wv = make_float4(0.f, 0.f, 0.f, 0.f);
        if (n < N) wv = *(const float4*)&Wt[n * K + kt + kq];
        Bs[kq + 0][r] = wv.x; Bs[kq + 1][r] = wv.y;
        Bs[kq + 2][r] = wv.z; Bs[kq + 3][r] = wv.w;
        __syncthreads();
#pragma unroll
        for (int k = 0; k < 16; k++) {
            float4 a = *(const float4*)&As[k][ty << 2];
            float4 b = *(const float4*)&Bs[k][tx << 2];
            acc[0][0] += a.x * b.x; acc[0][1] += a.x * b.y;
            acc[0][2] += a.x * b.z; acc[0][3] += a.x * b.w;
            acc[1][0] += a.y * b.x; acc[1][1] += a.y * b.y;
            acc[1][2] += a.y * b.z; acc[1][3] += a.y * b.w;
            acc[2][0] += a.z * b.x; acc[2][1] += a.z * b.y;
            acc[2][2] += a.z * b.z; acc[2][3] += a.z * b.w;
            acc[3][0] += a.w * b.x; acc[3][1] += a.w * b.y;
            acc[3][2] += a.w * b.z; acc[3][3] += a.w * b.w;
        }
        __syncthreads();
    }

#pragma unroll
    for (int ii = 0; ii < 4; ii++) {
        int m = bm + (ty << 2) + ii;
#pragma unroll
        for (int jj = 0; jj < 4; jj++) {
            int n = bn + (tx << 2) + jj;
            if (n < N) C[m * N + n] = acc[ii][jj] + bias[n];
        }
    }
}

// ---------------------------------------------------------------------------
// Kernel 3: persistent MFMA BLSTM, fence-free agent-scope coherence.
//  Round-8 changes: direct-to-register h loads via asm sc1 dwordx4 (full
//  MLP, no LDS staging), aggregated per-direction arrival counter,
//  gx prefetch issued before the poll, fast activations.
// ---------------------------------------------------------------------------
__global__ __launch_bounds__(256) void lstm_mfma3(
    const float* __restrict__ gxf, const float* __restrict__ gxb,
    const float* __restrict__ whh_f, const float* __restrict__ whh_b,
    unsigned int* __restrict__ hbuf,         // [2 buf][2 dir][32][256] u32
    _Float16* __restrict__ hcat_h,           // [4096][1024] fp16
    unsigned int* __restrict__ flags)        // [dir*32] arrival counters
{
    __shared__ float gl[4 * 32 * 17];        // gate exchange

    int bx = blockIdx.x;
    int dir = bx >> 5;
    int U0 = (bx & 31) * 16;
    int tid = threadIdx.x;
    int g = tid >> 6;              // wave = gate (i,f,g,o)
    int l = tid & 63;
    int lr = l & 15, lk = l >> 4;  // frag row / k-chunk

    const float* gx = dir ? gxb : gxf;

    // A-fragments: rows g*512+U0+lr, k = ks*32 + lk*8 .. +7 (f32 -> f16)
    half8 afrag[16];
    {
        const float* wrow = (dir ? whh_b : whh_f)
                          + (size_t)(g * 512 + U0 + lr) * 512 + lk * 8;
#pragma unroll
        for (int ks = 0; ks < 16; ks++) {
            float4 a = *(const float4*)(wrow + ks * 32);
            float4 b = *(const float4*)(wrow + ks * 32 + 4);
            afrag[ks] = cvt8(a, b);
        }
    }

    int uu = tid & 15, ub = tid >> 4;   // update map: unit uu, batches ub/ub+16
    float c0 = 0.f, c1 = 0.f;
    unsigned int* cntp = flags + dir * 32;   // one counter per direction

    for (int t = 0; t < L_; t++) {
        // ---- gx prefetch (independent of h; hides under the poll wait)
        float gxv0[4], gxv1[4];
        {
            const float* gxt = gx + (size_t)t * B_ * G4_;
#pragma unroll
            for (int gg = 0; gg < 4; gg++) {
                gxv0[gg] = gxt[ub * G4_ + gg * H_ + U0 + uu];
                gxv1[gg] = gxt[(ub + 16) * G4_ + gg * H_ + U0 + uu];
            }
        }

        // ---- wait for peers' h_{t-1}: single aggregated counter
        if (t > 0) {
            unsigned tgt = (unsigned)(32 * t);
            while (ld_u32_sc1(cntp) < tgt)
                __builtin_amdgcn_s_sleep(1);
            __builtin_amdgcn_sched_barrier(0);
        }

        // ---- direct-to-register h loads (sc1, full MLP), then MFMA
        const char* hsrc = (const char*)(hbuf
                         + ((((t + 1) & 1) * 2 + dir) * (32 * 256)));
        const char* hb0 = hsrc + lr * 1024 + lk * 16;
        const char* hb1 = hb0 + 16 * 1024;
        half8 fb0[16], fb1[16];
#pragma unroll
        for (int ks = 0; ks < 16; ks++) {
            fb0[ks] = ld_b128_sc1(hb0 + ks * 64);
            fb1[ks] = ld_b128_sc1(hb1 + ks * 64);
        }
        asm volatile("s_waitcnt vmcnt(0)" ::: "memory");
        __builtin_amdgcn_sched_barrier(0);

        f32x4 d0 = {0.f, 0.f, 0.f, 0.f};
        f32x4 d1 = {0.f, 0.f, 0.f, 0.f};
#pragma unroll
        for (int ks = 0; ks < 16; ks++) {
            d0 = __builtin_amdgcn_mfma_f32_16x16x32_f16(afrag[ks], fb0[ks], d0, 0, 0, 0);
            d1 = __builtin_amdgcn_mfma_f32_16x16x32_f16(afrag[ks], fb1[ks], d1, 0, 0, 0);
        }
#pragma unroll
        for (int r = 0; r < 4; r++) {
            gl[(g * 32 + lr) * 17 + lk * 4 + r]      = d0[r];
            gl[(g * 32 + 16 + lr) * 17 + lk * 4 + r] = d1[r];
        }
        __syncthreads();

        // ---- cell update: (b=ub, j=U0+uu) and (b=ub+16, j)
        {
            float ga0[4], ga1[4];
#pragma unroll
            for (int gg = 0; gg < 4; gg++) {
                ga0[gg] = gl[(gg * 32 + ub) * 17 + uu] + gxv0[gg];
                ga1[gg] = gl[(gg * 32 + ub + 16) * 17 + uu] + gxv1[gg];
            }
            float i0 = sigm_f(ga0[0]);
            float f0_ = sigm_f(ga0[1]);
            float g0 = tanh_f(ga0[2]);
            float o0 = sigm_f(ga0[3]);
            c0 = f0_ * c0 + i0 * g0;
            float h0 = o0 * tanh_f(c0);

            float i1 = sigm_f(ga1[0]);
            float f1_ = sigm_f(ga1[1]);
            float g1 = tanh_f(ga1[2]);
            float o1 = sigm_f(ga1[3]);
            c1 = f1_ * c1 + i1 * g1;
            float h1 = o1 * tanh_f(c1);

            int j = U0 + uu;
            int ll = dir ? (L_ - 1 - t) : t;
            hcat_h[((size_t)ub * L_ + ll) * (2 * H_) + dir * H_ + j]        = (_Float16)h0;
            hcat_h[((size_t)(ub + 16) * L_ + ll) * (2 * H_) + dir * H_ + j] = (_Float16)h1;

            // pack (j, j^1) fp16 pairs across even/odd lanes, sc1-store
            float h0n = __shfl_xor(h0, 1);
            float h1n = __shfl_xor(h1, 1);
            if ((uu & 1) == 0) {
                union { _Float16 h[2]; unsigned u; } p0, p1;
                p0.h[0] = (_Float16)h0; p0.h[1] = (_Float16)h0n;
                p1.h[0] = (_Float16)h1; p1.h[1] = (_Float16)h1n;
                unsigned int* hdst = hbuf + (((t & 1) * 2 + dir) * (32 * 256));
                int wj = (U0 + uu) >> 1;
                __hip_atomic_store(&hdst[ub * 256 + wj], p0.u,
                                   __ATOMIC_RELAXED, AGENT_SC);
                __hip_atomic_store(&hdst[(ub + 16) * 256 + wj], p1.u,
                                   __ATOMIC_RELAXED, AGENT_SC);
            }
        }

        // ---- arrive: syncthreads drains vmcnt(0) -> all h stores at MALL
        if (t < L_ - 1) {
            __syncthreads();
            if (tid == 0)
                __hip_atomic_fetch_add(cntp, 1u, __ATOMIC_RELAXED, AGENT_SC);
        }
    }
}

// ---------------------------------------------------------------------------
// Launch
// ---------------------------------------------------------------------------
extern "C" void kernel_launch(void* const* d_in, const int* in_sizes, int n_in,
                              void* d_out, int out_size, void* d_ws, size_t ws_size,
                              hipStream_t stream)
{
    const int*   word_ids = (const int*)d_in[0];
    const int*   char_ids = (const int*)d_in[1];
    const float* char_emb = (const float*)d_in[3];
    const float* word_emb = (const float*)d_in[4];
    const float* conv_w   = (const float*)d_in[5];
    const float* conv_b   = (const float*)d_in[6];
    const float* w_ih_f   = (const float*)d_in[7];
    const float* w_hh_f   = (const float*)d_in[8];
    const float* b_f      = (const float*)d_in[9];
    const float* w_ih_b   = (const float*)d_in[10];
    const float* w_hh_b   = (const float*)d_in[11];
    const float* b_b      = (const float*)d_in[12];
    const float* w1       = (const float*)d_in[13];
    const float* b1       = (const float*)d_in[14];
    const float* w2       = (const float*)d_in[15];
    const float* b2       = (const float*)d_in[16];
    float* out = (float*)d_out;
    float* ws  = (float*)d_ws;

    // workspace layout (f32 offsets)
    _Float16* x_h   = (_Float16*)(ws + 0);            // [4096][384] fp16
    float* gxf  = ws + 786432;       // [128][32][2048] f32
    float* gxb  = ws + 9175040;      // [128][32][2048] f32
    _Float16* hcat_h = (_Float16*)(ws + 17563648);    // [4096][1024] fp16
    float* z    = ws + 19660800;     // [4096][512] f32
    unsigned int* hbuf = (unsigned int*)(ws + 21757952);  // [2][2][32][256] u32
    float* cwT  = ws + 21823488;     // [64][3][128]
    unsigned int* flags = (unsigned int*)(ws + 21848064); // [64]

    hipMemsetAsync(hbuf, 0, 2 * 2 * 32 * 256 * sizeof(unsigned int), stream);
    hipMemsetAsync(flags, 0, 64 * sizeof(unsigned int), stream);

    conv_transpose_k<<<96, 256, 0, stream>>>(conv_w, cwT);
    embed_cnn<<<4096, 64, 0, stream>>>(word_ids, char_ids, char_emb, word_emb,
                                       cwT, conv_b, x_h);

    // input projections -> gx (time-major f32), fp16 MFMA
    dim3 g1(64, 32);
    gemm_f16<<<g1, 256, 0, stream>>>(x_h, w_ih_f, b_f, gxf, G4_, E_, 1, 0, 0);
    gemm_f16<<<g1, 256, 0, stream>>>(x_h, w_ih_b, b_b, gxb, G4_, E_, 2, 0, 0);

    {
        const float* a0 = gxf; const float* a1 = gxb;
        const float* a2 = w_hh_f; const float* a3 = w_hh_b;
        unsigned int* a4 = hbuf;
        _Float16* a5 = hcat_h;
        unsigned int* a6 = flags;
        void* args[] = { &a0, &a1, &a2, &a3, &a4, &a5, &a6 };
        hipLaunchCooperativeKernel((void*)lstm_mfma3, dim3(LSTM_BLOCKS), dim3(256),
                                   args, 0, stream);
    }

    // head1: z = ELU(hcat @ w1^T + b1), fp16 MFMA, fp32 out
    dim3 g2(64, 8);
    gemm_f16<<<g2, 256, 0, stream>>>(hcat_h, w1, b1, z, O1_, 2 * H_, 0, 1, 0);
    // head2: out = z @ w2^T + b2 (small fp32)
    dim3 g3(64, 1);
    gemm_bias_act<<<g3, 256, 0, stream>>>(z, w2, b2, out, 4096, NC_, O1_);
}

// Round 9
// 665.968 us; speedup vs baseline: 1.5596x; 1.5596x over previous
//
#include <hip/hip_runtime.h>
#include <math.h>

// Problem constants
#define B_   32
#define L_   128
#define W_   16
#define CE_  64     // char embed
#define NF_  128    // num filters
#define WE_  256    // word embed
#define E_   384    // NF_ + WE_
#define H_   512
#define G4_  2048   // 4*H
#define O1_  512
#define NC_  17
#define LSTM_BLOCKS 64          // 32 per direction
#define AGENT_SC __HIP_MEMORY_SCOPE_AGENT

typedef __attribute__((ext_vector_type(4))) float f32x4;
typedef _Float16 half8 __attribute__((ext_vector_type(8)));
typedef _Float16 half4 __attribute__((ext_vector_type(4)));

__device__ inline half8 cvt8(float4 a, float4 b) {
    half8 r;
    r[0] = (_Float16)a.x; r[1] = (_Float16)a.y;
    r[2] = (_Float16)a.z; r[3] = (_Float16)a.w;
    r[4] = (_Float16)b.x; r[5] = (_Float16)b.y;
    r[6] = (_Float16)b.z; r[7] = (_Float16)b.w;
    return r;
}

// sc1 (agent-coherent, MALL-direct) loads via inline asm
__device__ inline unsigned int ld_u32_sc1(const unsigned int* p) {
    unsigned int v;
    asm volatile("global_load_dword %0, %1, off sc1\n\ts_waitcnt vmcnt(0)"
                 : "=v"(v) : "v"(p) : "memory");
    return v;
}
__device__ inline half8 ld_b128_sc1(const void* p) {
    half8 v;
    asm volatile("global_load_dwordx4 %0, %1, off sc1"
                 : "=v"(v) : "v"(p) : "memory");
    return v;
}

__device__ inline float sigm_f(float x) { return 1.f / (1.f + __expf(-x)); }
__device__ inline float tanh_f(float x) { return 2.f / (1.f + __expf(-2.f * x)) - 1.f; }

// ---------------------------------------------------------------------------
// Kernel 0: transpose conv weights [F][C][K] -> [C][K][F]
// ---------------------------------------------------------------------------
__global__ __launch_bounds__(256) void conv_transpose_k(
    const float* __restrict__ cw, float* __restrict__ cwT)
{
    int i = blockIdx.x * 256 + threadIdx.x;   // 24576 exact
    int f = i / 192;
    int rem = i - f * 192;
    int c = rem / 3;
    int k = rem - c * 3;
    cwT[(c * 3 + k) * NF_ + f] = cw[i];
}

// ---------------------------------------------------------------------------
// Kernel 1: char embed gather + conv1d(k=3,pad=1) + relu + maxpool + word
// embed concat -> x_h [B*L, 384] fp16
// ---------------------------------------------------------------------------
__global__ __launch_bounds__(64) void embed_cnn(
    const int* __restrict__ word_ids, const int* __restrict__ char_ids,
    const float* __restrict__ char_emb, const float* __restrict__ word_emb,
    const float* __restrict__ cwT, const float* __restrict__ conv_b,
    _Float16* __restrict__ x_h)
{
    __shared__ float ce[CE_][20];
    __shared__ int ids[W_];
    int bl = blockIdx.x;
    int tid = threadIdx.x;

    if (tid < W_) ids[tid] = char_ids[bl * W_ + tid];
    ce[tid][0] = 0.f;
    ce[tid][17] = 0.f;
    __syncthreads();

    for (int i = tid; i < W_ * CE_; i += 64) {
        int w = i >> 6, c = i & 63;
        ce[c][w + 1] = char_emb[ids[w] * CE_ + c];
    }
    __syncthreads();

    int f0 = tid, f1 = tid + 64;
    float acc0[W_], acc1[W_];
#pragma unroll
    for (int w = 0; w < W_; w++) { acc0[w] = 0.f; acc1[w] = 0.f; }

    for (int c = 0; c < CE_; c++) {
        float win[18];
        float4 v0 = *(const float4*)&ce[c][0];
        float4 v1 = *(const float4*)&ce[c][4];
        float4 v2 = *(const float4*)&ce[c][8];
        float4 v3 = *(const float4*)&ce[c][12];
        win[0]=v0.x; win[1]=v0.y; win[2]=v0.z; win[3]=v0.w;
        win[4]=v1.x; win[5]=v1.y; win[6]=v1.z; win[7]=v1.w;
        win[8]=v2.x; win[9]=v2.y; win[10]=v2.z; win[11]=v2.w;
        win[12]=v3.x; win[13]=v3.y; win[14]=v3.z; win[15]=v3.w;
        win[16] = ce[c][16];
        win[17] = ce[c][17];
        const float* wp = cwT + c * 3 * NF_;
        float k00 = wp[f0], k01 = wp[NF_ + f0], k02 = wp[2 * NF_ + f0];
        float k10 = wp[f1], k11 = wp[NF_ + f1], k12 = wp[2 * NF_ + f1];
#pragma unroll
        for (int w = 0; w < W_; w++) {
            acc0[w] += win[w] * k00 + win[w + 1] * k01 + win[w + 2] * k02;
            acc1[w] += win[w] * k10 + win[w + 1] * k11 + win[w + 2] * k12;
        }
    }
    float m0 = acc0[0], m1 = acc1[0];
#pragma unroll
    for (int w = 1; w < W_; w++) { m0 = fmaxf(m0, acc0[w]); m1 = fmaxf(m1, acc1[w]); }
    m0 = fmaxf(0.f, m0 + conv_b[f0]);
    m1 = fmaxf(0.f, m1 + conv_b[f1]);
    x_h[bl * E_ + f0] = (_Float16)m0;
    x_h[bl * E_ + f1] = (_Float16)m1;

    int wid = word_ids[bl];
    float4 wv = *(const float4*)&word_emb[wid * WE_ + tid * 4];
    half4 h;
    h[0] = (_Float16)wv.x; h[1] = (_Float16)wv.y;
    h[2] = (_Float16)wv.z; h[3] = (_Float16)wv.w;
    *(half4*)&x_h[bl * E_ + NF_ + tid * 4] = h;
}

// ---------------------------------------------------------------------------
// Shared fp16 MFMA GEMM body.  C = A[M,K]h @ W[N,K]f32^T + bias.
// 64x64 tile, 4 waves, XOR-swizzled LDS, 16x16x32 MFMA.
// mode 0: C[m][n]; 1/2: C[(l or 127-l)*B + b][n].
// ---------------------------------------------------------------------------
__device__ __forceinline__ void gemm_f16_body(
    const _Float16* A, const float* Wt, const float* bias, void* C,
    int bm, int bn, int N, int K, int mode, int act, int fp16out)
{
    __shared__ _Float16 As[64 * 32];
    __shared__ _Float16 Bs[64 * 32];
    int tid = threadIdx.x;
    int l = tid & 63;
    int mt = tid >> 6;             // wave id = m-tile
    int lr = l & 15, lk = l >> 4;

    int srow = tid >> 2, skq = (tid & 3) << 3;   // staging: row 0..63, k 0..31
    int sbyteA = ((srow * 64 + skq * 2) ^ ((srow & 7) << 4));

    f32x4 d[4] = {{0.f,0.f,0.f,0.f},{0.f,0.f,0.f,0.f},
                  {0.f,0.f,0.f,0.f},{0.f,0.f,0.f,0.f}};

    for (int kt = 0; kt < K; kt += 32) {
        half8 av = *(const half8*)&A[(size_t)(bm + srow) * K + kt + skq];
        const float* wp = &Wt[(size_t)(bn + srow) * K + kt + skq];
        float4 w0 = *(const float4*)wp;
        float4 w1 = *(const float4*)(wp + 4);
        *(half8*)((char*)As + sbyteA) = av;
        *(half8*)((char*)Bs + sbyteA) = cvt8(w0, w1);
        __syncthreads();

        int arow = mt * 16 + lr;
        half8 af = *(const half8*)((char*)As +
                     ((arow * 64 + lk * 16) ^ ((arow & 7) << 4)));
#pragma unroll
        for (int nt = 0; nt < 4; nt++) {
            int brow = nt * 16 + lr;
            half8 bf = *(const half8*)((char*)Bs +
                         ((brow * 64 + lk * 16) ^ ((brow & 7) << 4)));
            d[nt] = __builtin_amdgcn_mfma_f32_16x16x32_f16(af, bf, d[nt], 0, 0, 0);
        }
        __syncthreads();
    }

#pragma unroll
    for (int nt = 0; nt < 4; nt++) {
        int n = bn + nt * 16 + lr;
        float bv = bias[n];
#pragma unroll
        for (int r = 0; r < 4; r++) {
            int m = bm + mt * 16 + lk * 4 + r;
            int orow;
            if (mode == 0) orow = m;
            else {
                int bb = m >> 7, ll = m & 127;
                if (mode == 2) ll = 127 - ll;
                orow = ll * B_ + bb;
            }
            float v = d[nt][r] + bv;
            if (act) v = v > 0.f ? v : expm1f(v);
            if (fp16out) ((_Float16*)C)[(size_t)orow * N + n] = (_Float16)v;
            else         ((float*)C)[(size_t)orow * N + n] = v;
        }
    }
}

__global__ __launch_bounds__(256) void gemm_f16(
    const _Float16* __restrict__ A, const float* __restrict__ Wt,
    const float* __restrict__ bias, void* __restrict__ C,
    int N, int K, int mode, int act, int fp16out)
{
    gemm_f16_body(A, Wt, bias, C, blockIdx.x * 64, blockIdx.y * 64,
                  N, K, mode, act, fp16out);
}

// Fused dual-direction input projection: blockIdx.y in [0,64); first 32
// n-tiles -> fwd (gxf, mode 1), last 32 -> bwd (gxb, mode 2).
__global__ __launch_bounds__(256) void gemm_f16_proj(
    const _Float16* __restrict__ A,
    const float* __restrict__ Wf, const float* __restrict__ Wb,
    const float* __restrict__ bf, const float* __restrict__ bb,
    float* __restrict__ gxf, float* __restrict__ gxb)
{
    int bng = blockIdx.y * 64;
    int dir = bng >> 11;               // 0: fwd, 1: bwd
    int bn  = bng & 2047;
    gemm_f16_body(A, dir ? Wb : Wf, dir ? bb : bf,
                  dir ? (void*)gxb : (void*)gxf,
                  blockIdx.x * 64, bn, G4_, E_, 1 + dir, 0, 0);
}

// ---------------------------------------------------------------------------
// Kernel 2b: small fp32 GEMM for the head2 (N=17)
// ---------------------------------------------------------------------------
__global__ __launch_bounds__(256) void gemm_bias_act(
    const float* __restrict__ A, const float* __restrict__ Wt,
    const float* __restrict__ bias, float* __restrict__ C,
    int M, int N, int K)
{
    __shared__ float As[16][68];
    __shared__ float Bs[16][68];
    int tid = threadIdx.x;
    int bm = blockIdx.x * 64;
    int bn = blockIdx.y * 64;
    int tx = tid & 15, ty = tid >> 4;
    int r = tid >> 2, kq = (tid & 3) << 2;
    float acc[4][4] = {};

    for (int kt = 0; kt < K; kt += 16) {
        float4 av = *(const float4*)&A[(bm + r) * K + kt + kq];
        As[kq + 0][r] = av.x; As[kq + 1][r] = av.y;
        As[kq + 2][r] = av.z; As[kq + 3][r] = av.w;
        int n = bn + r;
        float4 wv = make_float4(0.f, 0.f, 0.f, 0.f);
        if (n < N) wv = *(const float4*)&Wt[n * K + kt + kq];
        Bs[kq + 0][r] = wv.x; Bs[kq + 1][r] = wv.y;
        Bs[kq + 2][r] = wv.z; Bs[kq + 3][r] = wv.w;
        __syncthreads();
#pragma unroll
        for (int k = 0; k < 16; k++) {
            float4 a = *(const float4*)&As[k][ty << 2];
            float4 b = *(const float4*)&Bs[k][tx << 2];
            acc[0][0] += a.x * b.x; acc[0][1] += a.x * b.y;
            acc[0][2] += a.x * b.z; acc[0][3] += a.x * b.w;
            acc[1][0] += a.y * b.x; acc[1][1] += a.y * b.y;
            acc[1][2] += a.y * b.z; acc[1][3] += a.y * b.w;
            acc[2][0] += a.z * b.x; acc[2][1] += a.z * b.y;
            acc[2][2] += a.z * b.z; acc[2][3] += a.z * b.w;
            acc[3][0] += a.w * b.x; acc[3][1] += a.w * b.y;
            acc[3][2] += a.w * b.z; acc[3][3] += a.w * b.w;
        }
        __syncthreads();
    }

#pragma unroll
    for (int ii = 0; ii < 4; ii++) {
        int m = bm + (ty << 2) + ii;
#pragma unroll
        for (int jj = 0; jj < 4; jj++) {
            int n = bn + (tx << 2) + jj;
            if (n < N) C[m * N + n] = acc[ii][jj] + bias[n];
        }
    }
}

// ---------------------------------------------------------------------------
// Kernel 3: persistent MFMA BLSTM — round-7 protocol (per-block flags,
// LDS-staged h) + round-9 tweaks: padded flag lines, batched asm staging
// loads (8x dwordx4 sc1, single vmcnt drain), gx prefetch before the poll.
// ---------------------------------------------------------------------------
__global__ __launch_bounds__(256) void lstm_mfma4(
    const float* __restrict__ gxf, const float* __restrict__ gxb,
    const float* __restrict__ whh_f, const float* __restrict__ whh_b,
    unsigned int* __restrict__ hbuf,         // [2 buf][2 dir][32][256] u32
    _Float16* __restrict__ hcat_h,           // [4096][1024] fp16
    unsigned int* __restrict__ flags)        // [64 * 32] (128B per block)
{
    __shared__ unsigned int hlds[8192];      // 32 KB swizzled h
    __shared__ float gl[4 * 32 * 17];        // gate exchange

    int bx = blockIdx.x;
    int dir = bx >> 5;
    int U0 = (bx & 31) * 16;
    int tid = threadIdx.x;
    int g = tid >> 6;              // wave = gate (i,f,g,o)
    int l = tid & 63;
    int lr = l & 15, lk = l >> 4;  // frag row / k-chunk

    const float* gx = dir ? gxb : gxf;

    // A-fragments: rows g*512+U0+lr, k = ks*32 + lk*8 .. +7 (f32 -> f16)
    half8 afrag[16];
    {
        const float* wrow = (dir ? whh_b : whh_f)
                          + (size_t)(g * 512 + U0 + lr) * 512 + lk * 8;
#pragma unroll
        for (int ks = 0; ks < 16; ks++) {
            float4 a = *(const float4*)(wrow + ks * 32);
            float4 b = *(const float4*)(wrow + ks * 32 + 4);
            afrag[ks] = cvt8(a, b);
        }
    }

    int uu = tid & 15, ub = tid >> 4;   // update map: unit uu, batches ub/ub+16
    float c0 = 0.f, c1 = 0.f;
    const unsigned int* dflags = flags + dir * 32 * 32;  // padded: 32 u32/flag

    for (int t = 0; t < L_; t++) {
        // ---- gx prefetch (independent of h; hides under poll/stage waits)
        float gxv0[4], gxv1[4];
        {
            const float* gxt = gx + (size_t)t * B_ * G4_;
#pragma unroll
            for (int gg = 0; gg < 4; gg++) {
                gxv0[gg] = gxt[ub * G4_ + gg * H_ + U0 + uu];
                gxv1[gg] = gxt[(ub + 16) * G4_ + gg * H_ + U0 + uu];
            }
        }

        // ---- wait for peers' h_{t-1}: 32 padded flags, one per lane
        if (t > 0) {
            unsigned tgt = (unsigned)t;
            const unsigned int* fp = dflags + (tid & 31) * 32;
            while (ld_u32_sc1(fp) < tgt)
                __builtin_amdgcn_s_sleep(1);
            __builtin_amdgcn_sched_barrier(0);
        }

        // ---- stage h_{t-1} into swizzled LDS: 8 x dwordx4 sc1 per thread
        {
            const char* hsrc = (const char*)(hbuf
                             + ((((t + 1) & 1) * 2 + dir) * (32 * 256)));
            half8 tmp[8];
#pragma unroll
            for (int p = 0; p < 8; p++)
                tmp[p] = ld_b128_sc1(hsrc + p * 4096 + tid * 16);
            asm volatile("s_waitcnt vmcnt(0)" ::: "memory");
            __builtin_amdgcn_sched_barrier(0);
#pragma unroll
            for (int p = 0; p < 8; p++) {
                int o = p * 4096 + tid * 16;
                int row = o >> 10;
                *(half8*)((char*)hlds + (o ^ ((row & 7) << 4))) = tmp[p];
            }
        }
        __syncthreads();   // hlds ready

        // ---- MFMA: D[16 units][32 b] for this wave's gate
        f32x4 d0 = {0.f, 0.f, 0.f, 0.f};
        f32x4 d1 = {0.f, 0.f, 0.f, 0.f};
        const char* hb = (const char*)hlds;
        int base0 = lr * 1024 + lk * 16;
        int base1 = (16 + lr) * 1024 + lk * 16;
        int sw0 = (lr & 7) << 4;
#pragma unroll
        for (int ks = 0; ks < 16; ks++) {
            half8 b0 = *(const half8*)(hb + ((base0 + ks * 64) ^ sw0));
            half8 b1 = *(const half8*)(hb + ((base1 + ks * 64) ^ sw0));
            d0 = __builtin_amdgcn_mfma_f32_16x16x32_f16(afrag[ks], b0, d0, 0, 0, 0);
            d1 = __builtin_amdgcn_mfma_f32_16x16x32_f16(afrag[ks], b1, d1, 0, 0, 0);
        }
#pragma unroll
        for (int r = 0; r < 4; r++) {
            gl[(g * 32 + lr) * 17 + lk * 4 + r]      = d0[r];
            gl[(g * 32 + 16 + lr) * 17 + lk * 4 + r] = d1[r];
        }
        __syncthreads();

        // ---- cell update: (b=ub, j=U0+uu) and (b=ub+16, j)
        {
            float ga0[4], ga1[4];
#pragma unroll
            for (int gg = 0; gg < 4; gg++) {
                ga0[gg] = gl[(gg * 32 + ub) * 17 + uu] + gxv0[gg];
                ga1[gg] = gl[(gg * 32 + ub + 16) * 17 + uu] + gxv1[gg];
            }
            float i0 = sigm_f(ga0[0]);
            float f0_ = sigm_f(ga0[1]);
            float g0 = tanh_f(ga0[2]);
            float o0 = sigm_f(ga0[3]);
            c0 = f0_ * c0 + i0 * g0;
            float h0 = o0 * tanh_f(c0);

            float i1 = sigm_f(ga1[0]);
            float f1_ = sigm_f(ga1[1]);
            float g1 = tanh_f(ga1[2]);
            float o1 = sigm_f(ga1[3]);
            c1 = f1_ * c1 + i1 * g1;
            float h1 = o1 * tanh_f(c1);

            int j = U0 + uu;
            int ll = dir ? (L_ - 1 - t) : t;
            hcat_h[((size_t)ub * L_ + ll) * (2 * H_) + dir * H_ + j]        = (_Float16)h0;
            hcat_h[((size_t)(ub + 16) * L_ + ll) * (2 * H_) + dir * H_ + j] = (_Float16)h1;

            // pack (j, j^1) fp16 pairs across even/odd lanes, sc1-store
            float h0n = __shfl_xor(h0, 1);
            float h1n = __shfl_xor(h1, 1);
            if ((uu & 1) == 0) {
                union { _Float16 h[2]; unsigned u; } p0, p1;
                p0.h[0] = (_Float16)h0; p0.h[1] = (_Float16)h0n;
                p1.h[0] = (_Float16)h1; p1.h[1] = (_Float16)h1n;
                unsigned int* hdst = hbuf + (((t & 1) * 2 + dir) * (32 * 256));
                int wj = (U0 + uu) >> 1;
                __hip_atomic_store(&hdst[ub * 256 + wj], p0.u,
                                   __ATOMIC_RELAXED, AGENT_SC);
                __hip_atomic_store(&hdst[(ub + 16) * 256 + wj], p1.u,
                                   __ATOMIC_RELAXED, AGENT_SC);
            }
        }

        // ---- arrive: syncthreads drains vmcnt(0) -> all h stores at MALL
        __syncthreads();
        if (tid == 0)
            __hip_atomic_store(flags + bx * 32, (unsigned)(t + 1),
                               __ATOMIC_RELAXED, AGENT_SC);
    }
}

// ---------------------------------------------------------------------------
// Launch
// ---------------------------------------------------------------------------
extern "C" void kernel_launch(void* const* d_in, const int* in_sizes, int n_in,
                              void* d_out, int out_size, void* d_ws, size_t ws_size,
                              hipStream_t stream)
{
    const int*   word_ids = (const int*)d_in[0];
    const int*   char_ids = (const int*)d_in[1];
    const float* char_emb = (const float*)d_in[3];
    const float* word_emb = (const float*)d_in[4];
    const float* conv_w   = (const float*)d_in[5];
    const float* conv_b   = (const float*)d_in[6];
    const float* w_ih_f   = (const float*)d_in[7];
    const float* w_hh_f   = (const float*)d_in[8];
    const float* b_f      = (const float*)d_in[9];
    const float* w_ih_b   = (const float*)d_in[10];
    const float* w_hh_b   = (const float*)d_in[11];
    const float* b_b      = (const float*)d_in[12];
    const float* w1       = (const float*)d_in[13];
    const float* b1       = (const float*)d_in[14];
    const float* w2       = (const float*)d_in[15];
    const float* b2       = (const float*)d_in[16];
    float* out = (float*)d_out;
    float* ws  = (float*)d_ws;

    // workspace layout (f32 offsets)
    _Float16* x_h   = (_Float16*)(ws + 0);            // [4096][384] fp16
    float* gxf  = ws + 786432;       // [128][32][2048] f32
    float* gxb  = ws + 9175040;      // [128][32][2048] f32
    _Float16* hcat_h = (_Float16*)(ws + 17563648);    // [4096][1024] fp16
    float* z    = ws + 19660800;     // [4096][512] f32
    unsigned int* hbuf = (unsigned int*)(ws + 21757952);  // [2][2][32][256] u32
    float* cwT  = ws + 21823488;     // [64][3][128]
    unsigned int* flags = (unsigned int*)(ws + 21848064); // [64*32] padded

    hipMemsetAsync(hbuf, 0, 2 * 2 * 32 * 256 * sizeof(unsigned int), stream);
    hipMemsetAsync(flags, 0, 64 * 32 * sizeof(unsigned int), stream);

    conv_transpose_k<<<96, 256, 0, stream>>>(conv_w, cwT);
    embed_cnn<<<4096, 64, 0, stream>>>(word_ids, char_ids, char_emb, word_emb,
                                       cwT, conv_b, x_h);

    // fused input projections -> gxf/gxb (time-major f32), fp16 MFMA
    dim3 gp(64, 64);
    gemm_f16_proj<<<gp, 256, 0, stream>>>(x_h, w_ih_f, w_ih_b, b_f, b_b,
                                          gxf, gxb);

    {
        const float* a0 = gxf; const float* a1 = gxb;
        const float* a2 = w_hh_f; const float* a3 = w_hh_b;
        unsigned int* a4 = hbuf;
        _Float16* a5 = hcat_h;
        unsigned int* a6 = flags;
        void* args[] = { &a0, &a1, &a2, &a3, &a4, &a5, &a6 };
        hipLaunchCooperativeKernel((void*)lstm_mfma4, dim3(LSTM_BLOCKS), dim3(256),
                                   args, 0, stream);
    }

    // head1: z = ELU(hcat @ w1^T + b1), fp16 MFMA, fp32 out
    dim3 g2(64, 8);
    gemm_f16<<<g2, 256, 0, stream>>>(hcat_h, w1, b1, z, O1_, 2 * H_, 0, 1, 0);
    // head2: out = z @ w2^T + b2 (small fp32)
    dim3 g3(64, 1);
    gemm_bias_act<<<g3, 256, 0, stream>>>(z, w2, b2, out, 4096, NC_, O1_);
}